// Round 3
// baseline (1309.371 us; speedup 1.0000x reference)
//
#include <hip/hip_runtime.h>

#define IN_F   4096
#define OUT_F  4096
#define BWD    8
#define TAPS   17          // 2*BWD + 1
#define N_TOK  16384
#define TPB    256
#define OPT    2           // outputs per thread (one 8B store)
#define WIN    (OPT + 2*BWD)   // 18-float x window per thread
#define TN     32          // tokens per block strip

typedef float f2 __attribute__((ext_vector_type(2)));

// OPT=2: per-thread live set = 34 wreg + 2 breg + 2x18 window (double
// buffer) + acc + addressing ~= 86 regs. Fits the allocator's comfort zone
// (round-1 showed it refuses to go much past ~80-100), so the weights stay
// register-resident AND a 2-deep token pipeline fits. The round-1 OPT=4
// build needed ~100 live just single-buffered -> loads serialized, 292 us
// latency-bound (VALUBusy 10%).
__global__ __launch_bounds__(TPB, 4)
void BandLinear_kernel(const float* __restrict__ x,
                       const float* __restrict__ w,
                       const float* __restrict__ bias,
                       float* __restrict__ out) {
    const int g  = blockIdx.x * TPB + threadIdx.x;  // output-pair index, 0..2047
    const int o0 = g * OPT;                         // first output col
    const int n0 = blockIdx.y * TN;                 // first token of this strip

    // ---- band weights + bias into registers (once per block strip) ----
    float wreg[OPT][TAPS];
    float breg[OPT];
#pragma unroll
    for (int j = 0; j < OPT; ++j) {
        const int o = o0 + j;
        breg[j] = bias[o];
        const float* wrow = w + (size_t)o * IN_F;
#pragma unroll
        for (int t = 0; t < TAPS; ++t) {
            const int c = o + t - BWD;
            wreg[j][t] = (c >= 0 && c < IN_F) ? wrow[c] : 0.0f;
        }
    }

    const bool edge = (o0 - BWD < 0) || (o0 + OPT - 1 + BWD >= IN_F);

    // window start o0-8 -> byte offset 8*g - 32: 8B aligned -> float2 loads
    auto loadwin = [&](float (&xv)[WIN], int n) {
        const float* xr = x + (size_t)n * IN_F;
        if (!edge) {
            const f2* p = (const f2*)(xr + (o0 - BWD));
#pragma unroll
            for (int k = 0; k < WIN / 2; ++k) {
                f2 v = p[k];
                xv[2 * k + 0] = v.x;
                xv[2 * k + 1] = v.y;
            }
        } else {
            // row-edge pairs: clamped scalar loads (their OOB weights are 0)
#pragma unroll
            for (int k = 0; k < WIN; ++k) {
                int c = o0 - BWD + k;
                c = c < 0 ? 0 : (c >= IN_F ? IN_F - 1 : c);
                xv[k] = xr[c];
            }
        }
    };

    auto comp = [&](const float (&xv)[WIN], int n) {
        float a0 = breg[0];
        float a1 = breg[1];
#pragma unroll
        for (int t = 0; t < TAPS; ++t) {
            a0 = fmaf(wreg[0][t], xv[t + 0], a0);
            a1 = fmaf(wreg[1][t], xv[t + 1], a1);
        }
        f2 r; r.x = a0; r.y = a1;
        __builtin_nontemporal_store(r, (f2*)(out + (size_t)n * OUT_F + o0));
    };

    // ---- 2-deep software pipeline over the token strip ----
    float A[WIN], B[WIN];
    loadwin(A, n0);
    for (int tt = 0; tt < TN; tt += 2) {
        const int nA = n0 + tt;
        const int nB = n0 + tt + 1;                 // always < N_TOK (TN even)
        int nA2 = n0 + tt + 2;                      // next-next token prefetch
        if (nA2 >= N_TOK) nA2 = N_TOK - 1;          // clamp on last strip
        loadwin(B, nB);      // issue token t+1 loads...
        comp(A, nA);         // ...hidden under token t compute
        loadwin(A, nA2);
        comp(B, nB);
    }
}

extern "C" void kernel_launch(void* const* d_in, const int* in_sizes, int n_in,
                              void* d_out, int out_size, void* d_ws, size_t ws_size,
                              hipStream_t stream) {
    const float* x    = (const float*)d_in[0];
    const float* w    = (const float*)d_in[1];
    const float* bias = (const float*)d_in[2];
    // d_in[3] is the band mask; its structure (|i-j| <= 8) is hardcoded.
    float* out = (float*)d_out;

    dim3 grid(OUT_F / (TPB * OPT), N_TOK / TN);  // (8, 512)
    BandLinear_kernel<<<grid, TPB, 0, stream>>>(x, w, bias, out);
}